// Round 5
// baseline (172.687 us; speedup 1.0000x reference)
//
#include <hip/hip_runtime.h>

#define NRBF 20
#define FOUT 16
#define NA 768
#define NB 4
#define NT 48            // m-tiles per row (768/16)
#define TPW 12           // tiles per wave (NT/4)

// Round-8: MFMA compute + LANE-CONSECUTIVE stores (the fill's access shape).
//
// Diagnosis triangulated over R5-R7: halving compute (R6) and reshaping store
// instructions (R7) both left the kernel at ~66us vs a 24us write floor, while
// the harness's own fill sustains 6.5 TB/s on the same buffer. The one thing
// every variant shared: no quarter-wave ever covered a full 128B line in one
// instruction (R7's f32x4 store puts lane l at byte (l&15)*64+(l>>4)*16 ->
// 16 lines x 16B per quarter-wave). Theory: partial-line wave-stores cost
// multiple L2 granule slots (or sector-fetch) -> ~2.5x write-path penalty.
//
// Fix: one cross-lane permute turns the MFMA D-layout into the dense layout.
//   D (swapped operands, HW-validated R6/R7): lane s holds (m = s&15,
//   f = 4*(s>>4)+r, r=0..3). Dense target: lane l stores dwords 4l..4l+3 of
//   the tile's 1KB span = (m = l>>2, f = 4*(l&3)+r). Source lane:
//   s = ((l&3)<<4) | (l>>2). Four __shfl (ds_bpermute, LDS pipe, hidden under
//   the neighbor tile's exp chain) + one f32x4 store: quarter-wave = 256B
//   contiguous, wave = 1KB contiguous, every 128B line fully covered by one
//   instruction -- exactly the fill's shape. NT hint dropped (neutral in R7).
//
// Everything else unchanged from R7 (validated): gauge k = (l>>4)*8 + j,
// geometric recurrence r_{k+1} = r_k * t, t *= e^{-0.2}, 7 serial steps per
// lane; raw v_sqrt_f32; wave-contiguous 12KB write streams; bias as C-in.

typedef _Float16 f16x8 __attribute__((ext_vector_type(8)));
typedef float    f32x4 __attribute__((ext_vector_type(4)));

__global__ __launch_bounds__(256, 8) void cfconv_kernel(
    const float* __restrict__ coords,  // [NB, NA, 3] fp32
    const float* __restrict__ Ww,      // [FOUT, NRBF] fp32
    const float* __restrict__ Wb,      // [FOUT] fp32
    float* __restrict__ out)           // [NB, NA, NA, FOUT] fp32
{
    __shared__ float cm[NA * 3];       // batch's m-coordinates

    const int tid = threadIdx.x;
    const int n   = blockIdx.x;
    const int b   = blockIdx.y;

    const float* cb = coords + (size_t)b * NA * 3;
    for (int i = tid; i < NA * 3; i += 256) cm[i] = cb[i];
    __syncthreads();

    const int w  = tid >> 6;   // wave id 0..3 -> owns tiles w*12 .. w*12+11
    const int l  = tid & 63;
    const int mi = l & 15;     // m sub-index (B col / D col)
    const int g  = l >> 4;     // k-group; lane's D rows are f = 4g+0..3

    // A fragment = W[f = mi][k = 8g+j], zero-padded k >= 20 (L2-hot loads)
    f16x8 afrag;
    #pragma unroll
    for (int j = 0; j < 8; ++j) {
        const int k = g * 8 + j;
        afrag[j] = (k < NRBF) ? (_Float16)Ww[mi * NRBF + k] : (_Float16)0.0f;
    }
    // C-in rows are f = 4g+r -> bias per reg
    const f32x4 cinit = { Wb[4*g+0], Wb[4*g+1], Wb[4*g+2], Wb[4*g+3] };

    const float xn = cb[n*3+0];   // block-uniform -> scalar loads
    const float yn = cb[n*3+1];
    const float zn = cb[n*3+2];

    const float mu0  = 0.1f * (8 * g);          // segment-start mu
    const float tcst = 0.2f * (8 * g) + 0.1f;   // t_{k0+1} exponent offset
    const float u    = 0.81873075308f;          // e^{-0.2}

    // source lane for the dense-store permute (pull: this lane reads lane s)
    const int srcLane = ((l & 3) << 4) | (l >> 2);

    // lane's dense store slot: tile base + l*16B
    float* obase = out + (((size_t)b * NA + n) * NA) * FOUT + l * 4;

    #pragma unroll 2
    for (int tt = 0; tt < TPW; ++tt) {
        const int t = w * TPW + tt;
        const int m = t * 16 + mi;
        // cm word idx 3m: 16 lanes stride-3, gcd(3,32)=1 -> distinct banks;
        // the 4 k-groups share addresses -> broadcast, no conflict.
        const float dx = xn - cm[m*3+0];
        const float dy = yn - cm[m*3+1];
        const float dz = zn - cm[m*3+2];
        const float d2 = fmaf(dx, dx, fmaf(dy, dy, dz * dz));
        const float d  = __builtin_amdgcn_sqrtf(d2);   // raw v_sqrt_f32

        const float dd = d - mu0;
        float r   = __expf(-10.0f * dd * dd);   // r_{k0}
        float tt2 = __expf(2.0f * d - tcst);    // ratio t_{k0+1}

        f16x8 bfrag;                            // B[k = 8g+j][m = mi]
        bfrag[0] = (_Float16)r;
        #pragma unroll
        for (int j = 1; j < 8; ++j) {
            r *= tt2;                           // r_{k0+j}
            tt2 *= u;
            bfrag[j] = (_Float16)r;
        }

        f32x4 acc = cinit;                      // D = W * RBF^T + bias
        acc = __builtin_amdgcn_mfma_f32_16x16x32_f16(afrag, bfrag, acc, 0, 0, 0);

        // permute D to lane-dense layout: lane l <- lane srcLane's 4 f-values
        f32x4 sv;
        sv[0] = __shfl(acc[0], srcLane);
        sv[1] = __shfl(acc[1], srcLane);
        sv[2] = __shfl(acc[2], srcLane);
        sv[3] = __shfl(acc[3], srcLane);

        // dense: lane l stores bytes [l*16, l*16+16) of the tile's 1KB span;
        // quarter-wave = 256B contiguous, full 128B lines per instruction.
        *reinterpret_cast<f32x4*>(obase + (size_t)t * 16 * FOUT) = sv;
    }
}

extern "C" void kernel_launch(void* const* d_in, const int* in_sizes, int n_in,
                              void* d_out, int out_size, void* d_ws, size_t ws_size,
                              hipStream_t stream) {
    const float* coords = (const float*)d_in[0];
    const float* Ww     = (const float*)d_in[1];
    const float* Wb     = (const float*)d_in[2];
    float* out          = (float*)d_out;

    dim3 grid(NA, NB);   // (n, b)
    cfconv_kernel<<<grid, 256, 0, stream>>>(coords, Ww, Wb, out);
}

// Round 6
// 156.326 us; speedup vs baseline: 1.1047x; 1.1047x over previous
//
#include <hip/hip_runtime.h>

#define NRBF 20
#define FOUT 16
#define NA 768
#define NB 4
#define TPW 12           // tiles per wave (48 tiles / 4 waves)

// Round-9: attack the LATENCY STRUCTURE, not the store path.
//
// Evidence recap (R5-R8): store instruction shape (R7), full-line coverage
// (R8), and total compute (R6, which actually kept per-wave work constant
// while halving wave count -- a latency-bound signature) all left the kernel
// at ~66-82us vs ~7us issue work and a ~24us write floor. Conclusion: the
// per-tile serial chain {ds_read cm ~120cy -> fma -> sqrt -> exp -> 7-step
// recurrence -> MFMA -> store} with only ~2 chains in flight per wave is the
// wall; SIMDs are ~90% stalled.
//
// Changes vs R7 (single variable: chain overlap):
//   1. No LDS, no __syncthreads. Each lane preloads its 12 tiles' coords
//      (36 floats, global, L2/L3-hot 36KB array) -> LDS latency leaves the
//      chain; no lgkmcnt in the loop at all (R8 showed store-waits coupling
//      to ds_read via the shared counter).
//   2. Phase split: all 12 distances first (12 independent fma->sqrt chains
//      overlap), then 12 independent {exp, recurrence, MFMA, store} chains
//      at unroll 4 -> 4-deep ILP x 6 waves/SIMD = ~24 chains in flight.
//   3. __launch_bounds__(256,6): 84-VGPR cap fits dv[12]+unroll-4 set.
//
// Validated pieces kept bit-identical: gauge k=(l>>4)*8+j fragments, W-side
// zero-pad, swapped-operand MFMA (D = W*RBF^T), R7 dense store addressing
// (lane -> (mi*FOUT+4g), wave covers permuted-contiguous 1KB), raw v_sqrt,
// bias as C-in, telescoped geometric recurrence.

typedef _Float16 f16x8 __attribute__((ext_vector_type(8)));
typedef float    f32x4 __attribute__((ext_vector_type(4)));

__global__ __launch_bounds__(256, 6) void cfconv_kernel(
    const float* __restrict__ coords,  // [NB, NA, 3] fp32
    const float* __restrict__ Ww,      // [FOUT, NRBF] fp32
    const float* __restrict__ Wb,      // [FOUT] fp32
    float* __restrict__ out)           // [NB, NA, NA, FOUT] fp32
{
    const int tid = threadIdx.x;
    const int n   = blockIdx.x;
    const int b   = blockIdx.y;

    const int w  = tid >> 6;   // wave id 0..3 -> owns tiles w*12 .. w*12+11
    const int l  = tid & 63;
    const int mi = l & 15;     // m sub-index (B col / D col)
    const int g  = l >> 4;     // k-group; lane's D rows are f = 4g+0..3

    const float* cb = coords + (size_t)b * NA * 3;

    // A fragment = W[f = mi][k = 8g+j], zero-padded k >= 20 (L2-hot loads)
    f16x8 afrag;
    #pragma unroll
    for (int j = 0; j < 8; ++j) {
        const int k = g * 8 + j;
        afrag[j] = (k < NRBF) ? (_Float16)Ww[mi * NRBF + k] : (_Float16)0.0f;
    }
    // C-in rows are f = 4g+r -> bias per reg
    const f32x4 cinit = { Wb[4*g+0], Wb[4*g+1], Wb[4*g+2], Wb[4*g+3] };

    const float xn = cb[n*3+0];   // block-uniform -> scalar loads
    const float yn = cb[n*3+1];
    const float zn = cb[n*3+2];

    // Phase 1: all 12 distances as independent chains. Coord loads are
    // per-lane global (16 unique addresses per instr, g-groups broadcast);
    // the 36KB coords array is L2/L3-resident after the first blocks.
    float dv[TPW];
    #pragma unroll
    for (int tt = 0; tt < TPW; ++tt) {
        const int m = (w * TPW + tt) * 16 + mi;
        const float dx = xn - cb[m*3+0];
        const float dy = yn - cb[m*3+1];
        const float dz = zn - cb[m*3+2];
        dv[tt] = __builtin_amdgcn_sqrtf(fmaf(dx, dx, fmaf(dy, dy, dz * dz)));
    }

    const float mu0  = 0.1f * (8 * g);          // segment-start mu
    const float tcst = 0.2f * (8 * g) + 0.1f;   // t_{k0+1} exponent offset
    const float u    = 0.81873075308f;          // e^{-0.2}

    // lane's store slot within each tile's 1KB span (R7 layout, validated)
    float* obase = out + (((size_t)b * NA + n) * NA + mi) * FOUT + 4 * g;

    // Phase 2: 12 independent {exp, recurrence, MFMA, store} chains, 4-deep
    #pragma unroll 4
    for (int tt = 0; tt < TPW; ++tt) {
        const int t = w * TPW + tt;
        const float d  = dv[tt];
        const float dd = d - mu0;
        float r = __expf(-10.0f * dd * dd);     // r_{k0}
        float q = __expf(2.0f * d - tcst);      // ratio t_{k0+1}

        f16x8 bfrag;                            // B[k = 8g+j][m = mi]
        bfrag[0] = (_Float16)r;
        #pragma unroll
        for (int j = 1; j < 8; ++j) {
            r *= q;                             // r_{k0+j}
            q *= u;
            bfrag[j] = (_Float16)r;
        }

        f32x4 acc =                             // D = W * RBF^T + bias
            __builtin_amdgcn_mfma_f32_16x16x32_f16(afrag, bfrag, cinit, 0, 0, 0);

        // dense: out[b, n, tile t, (mi, 4g..)] -- wave covers the 1KB span
        *reinterpret_cast<f32x4*>(obase + (size_t)t * 16 * FOUT) = acc;
    }
}

extern "C" void kernel_launch(void* const* d_in, const int* in_sizes, int n_in,
                              void* d_out, int out_size, void* d_ws, size_t ws_size,
                              hipStream_t stream) {
    const float* coords = (const float*)d_in[0];
    const float* Ww     = (const float*)d_in[1];
    const float* Wb     = (const float*)d_in[2];
    float* out          = (float*)d_out;

    dim3 grid(NA, NB);   // (n, b)
    cfconv_kernel<<<grid, 256, 0, stream>>>(coords, Ww, Wb, out);
}

// Round 7
// 155.232 us; speedup vs baseline: 1.1124x; 1.0070x over previous
//
#include <hip/hip_runtime.h>

#define NRBF 20
#define FOUT 16
#define NA 768
#define NB 4
#define TPW 12           // tiles per wave (48 tiles / 4 waves)

// Round-10: R9's zero-LDS latency structure + R8's lane-dense stores.
//
// Why revisit R8's idea: its +14us regression (~2800 cyc/wave) matches its 48
// ds_bpermutes serializing against cm ds_reads on the SHARED lgkm counter --
// a confound, not a falsification. R9 removed all LDS from the kernel, so the
// bpermutes are now the ONLY lgkm ops, independent across unroll-4 tiles
// (16 in flight), with nothing to couple against.
//
// Store-shape theory (the last one standing after R5-R9):
//   MFMA-layout store: lane l writes 16B at byte mi*64 + g*16 of the tile's
//   1KB -> each 16-lane quarter-wave touches 8 different 128B lines with 32B
//   each -> ~4x L2 write requests per byte vs the fill's dense pattern.
//   Permuted store: lane l <- lane ((l&3)<<4)|(l>>2) gives lane l dwords
//   4l..4l+3 -> quarter-wave = 256B contiguous = 2 FULL lines; wave = 1KB.
//   Both the permute map and dense addressing are correctness-validated (R8
//   passed with identical absmax).
//
// Everything else identical to R9 (best so far): no LDS/no barrier; per-lane
// coord preload; phase-split (12 independent dist chains, then 12 independent
// exp/recurrence/MFMA/store chains at unroll 4); gauge k=(l>>4)*8+j frags;
// W-side zero-pad; swapped-operand MFMA; raw v_sqrt; bias as C-in.

typedef _Float16 f16x8 __attribute__((ext_vector_type(8)));
typedef float    f32x4 __attribute__((ext_vector_type(4)));

__global__ __launch_bounds__(256, 6) void cfconv_kernel(
    const float* __restrict__ coords,  // [NB, NA, 3] fp32
    const float* __restrict__ Ww,      // [FOUT, NRBF] fp32
    const float* __restrict__ Wb,      // [FOUT] fp32
    float* __restrict__ out)           // [NB, NA, NA, FOUT] fp32
{
    const int tid = threadIdx.x;
    const int n   = blockIdx.x;
    const int b   = blockIdx.y;

    const int w  = tid >> 6;   // wave id 0..3 -> owns tiles w*12 .. w*12+11
    const int l  = tid & 63;
    const int mi = l & 15;     // m sub-index (B col / D col)
    const int g  = l >> 4;     // k-group; lane's D rows are f = 4g+0..3

    const float* cb = coords + (size_t)b * NA * 3;

    // A fragment = W[f = mi][k = 8g+j], zero-padded k >= 20 (L2-hot loads)
    f16x8 afrag;
    #pragma unroll
    for (int j = 0; j < 8; ++j) {
        const int k = g * 8 + j;
        afrag[j] = (k < NRBF) ? (_Float16)Ww[mi * NRBF + k] : (_Float16)0.0f;
    }
    // C-in rows are f = 4g+r -> bias per reg
    const f32x4 cinit = { Wb[4*g+0], Wb[4*g+1], Wb[4*g+2], Wb[4*g+3] };

    const float xn = cb[n*3+0];   // block-uniform -> scalar loads
    const float yn = cb[n*3+1];
    const float zn = cb[n*3+2];

    // Phase 1: all 12 distances as independent chains (coords L2/L3-hot).
    float dv[TPW];
    #pragma unroll
    for (int tt = 0; tt < TPW; ++tt) {
        const int m = (w * TPW + tt) * 16 + mi;
        const float dx = xn - cb[m*3+0];
        const float dy = yn - cb[m*3+1];
        const float dz = zn - cb[m*3+2];
        dv[tt] = __builtin_amdgcn_sqrtf(fmaf(dx, dx, fmaf(dy, dy, dz * dz)));
    }

    const float mu0  = 0.1f * (8 * g);          // segment-start mu
    const float tcst = 0.2f * (8 * g) + 0.1f;   // t_{k0+1} exponent offset
    const float u    = 0.81873075308f;          // e^{-0.2}

    // dense-store permute source lane (validated R8)
    const int srcLane = ((l & 3) << 4) | (l >> 2);
    // lane's dense slot: tile base + l*16B (validated R8)
    float* obase = out + (((size_t)b * NA + n) * NA) * FOUT + l * 4;

    // Phase 2: 12 independent {exp, recurrence, MFMA, permute, store} chains
    #pragma unroll 4
    for (int tt = 0; tt < TPW; ++tt) {
        const int t = w * TPW + tt;
        const float d  = dv[tt];
        const float dd = d - mu0;
        float r = __expf(-10.0f * dd * dd);     // r_{k0}
        float q = __expf(2.0f * d - tcst);      // ratio t_{k0+1}

        f16x8 bfrag;                            // B[k = 8g+j][m = mi]
        bfrag[0] = (_Float16)r;
        #pragma unroll
        for (int j = 1; j < 8; ++j) {
            r *= q;                             // r_{k0+j}
            q *= u;
            bfrag[j] = (_Float16)r;
        }

        f32x4 acc =                             // D = W * RBF^T + bias
            __builtin_amdgcn_mfma_f32_16x16x32_f16(afrag, bfrag, cinit, 0, 0, 0);

        // permute to lane-dense layout; only lgkm ops in the kernel, 4 tiles
        // of these pipeline independently under unroll-4
        f32x4 sv;
        sv[0] = __shfl(acc[0], srcLane);
        sv[1] = __shfl(acc[1], srcLane);
        sv[2] = __shfl(acc[2], srcLane);
        sv[3] = __shfl(acc[3], srcLane);

        // dense: lane l stores bytes [l*16, l*16+16) of the tile's 1KB span;
        // quarter-wave = 256B = 2 full 128B lines per instruction.
        *reinterpret_cast<f32x4*>(obase + (size_t)t * 16 * FOUT) = sv;
    }
}

extern "C" void kernel_launch(void* const* d_in, const int* in_sizes, int n_in,
                              void* d_out, int out_size, void* d_ws, size_t ws_size,
                              hipStream_t stream) {
    const float* coords = (const float*)d_in[0];
    const float* Ww     = (const float*)d_in[1];
    const float* Wb     = (const float*)d_in[2];
    float* out          = (float*)d_out;

    dim3 grid(NA, NB);   // (n, b)
    cfconv_kernel<<<grid, 256, 0, stream>>>(coords, Ww, Wb, out);
}